// Round 1
// baseline (570.984 us; speedup 1.0000x reference)
//
#include <hip/hip_runtime.h>
#include <math.h>

// Problem constants
#define Vv 32000
#define Ee 1024
#define Hh 1024
#define Aa 10
#define Ss 512
#define Bb 64

// ---------------------------------------------------------------------------
// hpart[b][a] = sum_k Wa1[a][k] * h_last[b][k]   (k in [0,1024): the "hh" half
// of feats). S-invariant, so computed once instead of 512x.
// grid(64), block(256)
__global__ __launch_bounds__(256) void hpart_kernel(const float* __restrict__ Wa1,
                                                    const float* __restrict__ h,
                                                    float* __restrict__ hpart) {
    __shared__ float red[256];
    const int b = blockIdx.x, t = threadIdx.x;
    float p[Aa];
#pragma unroll
    for (int a = 0; a < Aa; a++) p[a] = 0.f;
    for (int k = t; k < Hh; k += 256) {
        float hv = h[b * Hh + k];
#pragma unroll
        for (int a = 0; a < Aa; a++) p[a] += Wa1[a * (2 * Hh) + k] * hv;
    }
    for (int a = 0; a < Aa; a++) {
        red[t] = p[a];
        __syncthreads();
        for (int o = 128; o > 0; o >>= 1) {
            if (t < o) red[t] += red[t + o];
            __syncthreads();
        }
        if (t == 0) hpart[b * 16 + a] = red[0];
        __syncthreads();
    }
}

// ---------------------------------------------------------------------------
// scores: e[s*64+b] = sum_a Wa2[a] * tanh(hpart[b][a] + dot(Wa1_e[a], enc[s,b,:]))
// Block handles 64 rows (m = s*64+b, so the 64 rows of a block cover b=0..63).
// enc chunk staged in LDS with +1 pad (conflict-free b32 reads). Wave q of 4
// handles k-quarter [q*16, q*16+16) of each 64-wide chunk; Wa1 indices are
// wave-uniform (readfirstlane) -> scalar loads. 4 partials reduced via LDS.
// grid(512), block(256)
__global__ __launch_bounds__(256) void scores_kernel(const float* __restrict__ enc,
                                                     const float* __restrict__ Wa1,
                                                     const float* __restrict__ Wa2,
                                                     const float* __restrict__ hpart,
                                                     float* __restrict__ e_out) {
    __shared__ float es[64][65];       // 64 rows x 64-k chunk, +1 pad
    __shared__ float red[4][64][11];   // 4 wave-partials x 64 rows x 10 (+1 pad)
    const int t = threadIdx.x;
    const int m0 = blockIdx.x * 64;
    const int q = __builtin_amdgcn_readfirstlane((int)(t >> 6));  // wave id, uniform
    const int lane = t & 63;
    const float4* enc4 = (const float4*)enc;

    float acc[Aa];
#pragma unroll
    for (int a = 0; a < Aa; a++) acc[a] = 0.f;

    for (int c = 0; c < 16; c++) {  // 16 chunks of 64 k
        // stage 64 rows x 64 k (=1024 float4), 4 per thread
#pragma unroll
        for (int p = 0; p < 4; p++) {
            int idx = t + p * 256;
            int r = idx >> 4, kq = idx & 15;
            float4 v = enc4[(size_t)(m0 + r) * 256 + c * 16 + kq];
            es[r][kq * 4 + 0] = v.x;
            es[r][kq * 4 + 1] = v.y;
            es[r][kq * 4 + 2] = v.z;
            es[r][kq * 4 + 3] = v.w;
        }
        __syncthreads();
        const int kbase = Hh + c * 64 + q * 16;  // enc-half of Wa1 row (cols 1024..2047)
#pragma unroll
        for (int j = 0; j < 16; j++) {
            float ev = es[lane][q * 16 + j];
#pragma unroll
            for (int a = 0; a < Aa; a++)
                acc[a] += Wa1[a * (2 * Hh) + kbase + j] * ev;
        }
        __syncthreads();  // WAR before next stage
    }
#pragma unroll
    for (int a = 0; a < Aa; a++) red[q][lane][a] = acc[a];
    __syncthreads();
    if (t < 64) {
        // row r = t; b = (m0+t) & 63 = t since m0 is a multiple of 64
        float ev = 0.f;
#pragma unroll
        for (int a = 0; a < Aa; a++) {
            float tot = red[0][t][a] + red[1][t][a] + red[2][t][a] + red[3][t][a]
                        + hpart[t * 16 + a];
            ev += Wa2[a] * tanhf(tot);
        }
        e_out[m0 + t] = ev;
    }
}

// ---------------------------------------------------------------------------
// softmax over S per column b:  alpha[s,b] = softmax_s(e[s,b])
// grid(64), block(512): one thread per s
__global__ __launch_bounds__(512) void softmax_kernel(const float* __restrict__ e,
                                                      float* __restrict__ alpha) {
    __shared__ float red[512];
    const int b = blockIdx.x, s = threadIdx.x;
    float v = e[s * Bb + b];
    red[s] = v;
    __syncthreads();
    for (int o = 256; o > 0; o >>= 1) {
        if (s < o) red[s] = fmaxf(red[s], red[s + o]);
        __syncthreads();
    }
    float m = red[0];
    __syncthreads();
    float ex = expf(v - m);
    red[s] = ex;
    __syncthreads();
    for (int o = 256; o > 0; o >>= 1) {
        if (s < o) red[s] += red[s + o];
        __syncthreads();
    }
    float inv = 1.f / red[0];
    alpha[s * Bb + b] = ex * inv;
}

// ---------------------------------------------------------------------------
// context: c[b][h] = sum_s alpha[s,b] * enc[s,b,h]
// grid(64, 2, 4): x=b, y=h-chunk (2x512), z=s-chunk (4x128). block(128).
// s-split partials combined with device-scope f32 atomics (c memset to 0).
__global__ __launch_bounds__(128) void context_kernel(const float* __restrict__ enc,
                                                      const float* __restrict__ alpha,
                                                      float* __restrict__ c) {
    const int b = blockIdx.x, hc = blockIdx.y, sc = blockIdx.z;
    const int h4 = hc * 128 + threadIdx.x;  // float4 index in [0,256)
    const float4* enc4 = (const float4*)enc;
    float4 acc = {0.f, 0.f, 0.f, 0.f};
    const int s0 = sc * 128;
    for (int s = s0; s < s0 + 128; ++s) {
        float a = alpha[s * Bb + b];
        float4 ev = enc4[(size_t)(s * Bb + b) * 256 + h4];
        acc.x += a * ev.x;
        acc.y += a * ev.y;
        acc.z += a * ev.z;
        acc.w += a * ev.w;
    }
    float* cp = c + b * Hh + h4 * 4;
    atomicAdd(cp + 0, acc.x);
    atomicAdd(cp + 1, acc.y);
    atomicAdd(cp + 2, acc.z);
    atomicAdd(cp + 3, acc.w);
}

// ---------------------------------------------------------------------------
// xc[b] = [ emb[dec_input[b]] (1024) | c[b] (1024) ]
// grid(64), block(256)
__global__ __launch_bounds__(256) void xc_kernel(const int* __restrict__ dec_input,
                                                 const float* __restrict__ emb,
                                                 const float* __restrict__ c,
                                                 float* __restrict__ xc) {
    const int b = blockIdx.x, t = threadIdx.x;
    const int tok = dec_input[b];
    const float4* er = (const float4*)(emb + (size_t)tok * Ee);
    const float4* cr = (const float4*)(c + (size_t)b * Hh);
    float4* xr = (float4*)(xc + (size_t)b * (Ee + Hh));
    xr[t] = er[t];        // t in [0,256) covers 1024 floats
    xr[256 + t] = cr[t];
}

// ---------------------------------------------------------------------------
// Generic skinny GEMM: C[64][N] (+)= A[64][K] @ W[N][K]^T (+ bias)
// Block: 256 threads = 4 waves. Each wave owns an independent k-slice of
// length K/(gridDim.y*4) (multiple of 32) of the same 64x64 output tile,
// staged in its own LDS region (no cross-wave barrier needed per chunk, but
// barriers kept — uniform chunk counts). 8x8 micro-tile per thread with
// float4 LDS frag reads ([kk][row] layout). Waves reduced through LDS;
// k-split across blocks combined with global atomics (C pre-zeroed).
// Dynamic LDS: As 32KB | Ws 32KB, red (16KB) overlays As after compute.
__global__ __launch_bounds__(256) void gemm64_kernel(const float* __restrict__ A,
                                                     const float* __restrict__ Wt,
                                                     const float* __restrict__ bias,
                                                     float* __restrict__ C,
                                                     int N, int K, int doAtomic) {
    extern __shared__ __align__(16) float smem[];
    float* As = smem;            // [4][32][64]
    float* Ws = smem + 8192;     // [4][32][64]
    float* red = smem;           // [64][64], overlays As after compute phase

    const int t = threadIdx.x;
    const int w = __builtin_amdgcn_readfirstlane((int)(t >> 6));
    const int lane = t & 63;
    const int n0 = blockIdx.x * 64;
    const int slices = gridDim.y * 4;
    const int wslen = K / slices;  // multiple of 32 by construction
    const int ks = (blockIdx.y * 4 + w) * wslen;
    const int tx = lane & 7, ty = lane >> 3;

    float acc[8][8];
#pragma unroll
    for (int i = 0; i < 8; i++)
#pragma unroll
        for (int j = 0; j < 8; j++) acc[i][j] = 0.f;

    for (int kc = 0; kc < wslen; kc += 32) {
        const int kb = ks + kc;
        // stage A: As[w][kk][lane] = A[lane][kb+kk]  (row-read, transposed write)
        {
            const float* Arow = A + (size_t)lane * K + kb;
            const float* Wrow = Wt + (size_t)(n0 + lane) * K + kb;
#pragma unroll
            for (int kk = 0; kk < 32; kk += 4) {
                float4 va = *(const float4*)(Arow + kk);
                float* ab = As + w * 2048 + lane;
                ab[(kk + 0) * 64] = va.x;
                ab[(kk + 1) * 64] = va.y;
                ab[(kk + 2) * 64] = va.z;
                ab[(kk + 3) * 64] = va.w;
                float4 vw = *(const float4*)(Wrow + kk);
                float* wb = Ws + w * 2048 + lane;
                wb[(kk + 0) * 64] = vw.x;
                wb[(kk + 1) * 64] = vw.y;
                wb[(kk + 2) * 64] = vw.z;
                wb[(kk + 3) * 64] = vw.w;
            }
        }
        __syncthreads();
#pragma unroll
        for (int kk = 0; kk < 32; kk++) {
            const float4* a4 = (const float4*)(As + w * 2048 + kk * 64 + ty * 8);
            const float4* w4 = (const float4*)(Ws + w * 2048 + kk * 64 + tx * 8);
            float4 a0 = a4[0], a1 = a4[1];
            float4 b0 = w4[0], b1 = w4[1];
            float av[8] = {a0.x, a0.y, a0.z, a0.w, a1.x, a1.y, a1.z, a1.w};
            float wv[8] = {b0.x, b0.y, b0.z, b0.w, b1.x, b1.y, b1.z, b1.w};
#pragma unroll
            for (int i = 0; i < 8; i++)
#pragma unroll
                for (int j = 0; j < 8; j++) acc[i][j] += av[i] * wv[j];
        }
        __syncthreads();  // WAR before next stage
    }

    // cross-wave reduction into red[64][64] (overlays As: all compute done)
    for (int ww = 0; ww < 4; ww++) {
        if (w == ww) {
#pragma unroll
            for (int i = 0; i < 8; i++)
#pragma unroll
                for (int j = 0; j < 8; j++) {
                    int idx = (ty * 8 + i) * 64 + tx * 8 + j;
                    if (ww == 0) red[idx] = acc[i][j];
                    else red[idx] += acc[i][j];
                }
        }
        __syncthreads();
    }

    // store 4096 outputs with 256 threads
    for (int p = 0; p < 16; p++) {
        int idx = t + p * 256;
        int b = idx >> 6, nn = idx & 63;
        float v = red[b * 64 + nn];
        size_t co = (size_t)b * N + n0 + nn;
        if (doAtomic) atomicAdd(&C[co], v);
        else C[co] = v + (bias ? bias[n0 + nn] : 0.f);
    }
}

// ---------------------------------------------------------------------------
// GRU cell elementwise. gi/gh computed WITHOUT biases (atomic k-split), so
// biases applied here. n = tanh((gi_n + b_ih_n) + r*(gh_n + b_hh_n)).
// grid(256), block(256)
__global__ __launch_bounds__(256) void gru_kernel(const float* __restrict__ gi,
                                                  const float* __restrict__ gh,
                                                  const float* __restrict__ b_ih,
                                                  const float* __restrict__ b_hh,
                                                  const float* __restrict__ h,
                                                  float* __restrict__ h_new) {
    const int idx = blockIdx.x * 256 + threadIdx.x;  // 0..65535
    const int b = idx >> 10, j = idx & 1023;
    const size_t base = (size_t)b * (3 * Hh);
    float ir = gi[base + j] + b_ih[j];
    float iz = gi[base + Hh + j] + b_ih[Hh + j];
    float in_ = gi[base + 2 * Hh + j] + b_ih[2 * Hh + j];
    float hr = gh[base + j] + b_hh[j];
    float hz = gh[base + Hh + j] + b_hh[Hh + j];
    float hn = gh[base + 2 * Hh + j] + b_hh[2 * Hh + j];
    float r = 1.f / (1.f + expf(-(ir + hr)));
    float z = 1.f / (1.f + expf(-(iz + hz)));
    float n = tanhf(in_ + r * hn);
    h_new[idx] = (1.f - z) * n + z * h[idx];
}

// ---------------------------------------------------------------------------
extern "C" void kernel_launch(void* const* d_in, const int* in_sizes, int n_in,
                              void* d_out, int out_size, void* d_ws, size_t ws_size,
                              hipStream_t stream) {
    const int* dec_input = (const int*)d_in[0];
    const float* dec_hidden = (const float*)d_in[1];  // (1,B,H) -> h_last[b][h]
    const float* enc = (const float*)d_in[2];         // (S,B,H)
    const float* emb = (const float*)d_in[3];         // (V,E)
    const float* Wa1 = (const float*)d_in[4];         // (A, 2H)
    const float* Wa2 = (const float*)d_in[5];         // (1, A)
    const float* W_ih = (const float*)d_in[6];        // (3H, E+H)
    const float* W_hh = (const float*)d_in[7];        // (3H, H)
    const float* b_ih = (const float*)d_in[8];
    const float* b_hh = (const float*)d_in[9];
    const float* W_out = (const float*)d_in[10];      // (V, H)
    const float* b_out = (const float*)d_in[11];

    float* out = (float*)d_out;
    float* logits = out;                         // (B,V) = 64*32000
    float* h_new = out + (size_t)Bb * Vv;        // (1,B,H) = 64*1024

    float* ws = (float*)d_ws;
    float* e_ptr = ws;                  // 32768
    float* alpha_ptr = ws + 32768;      // 32768
    float* hpart_ptr = ws + 65536;      // 1024 (64 x 16)
    float* c_ptr = ws + 66560;          // 65536
    float* xc_ptr = ws + 132096;        // 131072
    float* gi_ptr = ws + 263168;        // 196608
    float* gh_ptr = ws + 459776;        // 196608
    // total 656384 floats = 2.63 MB of ws

    // zero atomic-accumulated buffers (ws/d_out are re-poisoned each call)
    hipMemsetAsync(c_ptr, 0, (size_t)Bb * Hh * sizeof(float), stream);
    hipMemsetAsync(gi_ptr, 0, (size_t)2 * Bb * 3 * Hh * sizeof(float), stream);

    hpart_kernel<<<Bb, 256, 0, stream>>>(Wa1, dec_hidden, hpart_ptr);
    scores_kernel<<<(Ss * Bb) / 64, 256, 0, stream>>>(enc, Wa1, Wa2, hpart_ptr, e_ptr);
    softmax_kernel<<<Bb, 512, 0, stream>>>(e_ptr, alpha_ptr);
    context_kernel<<<dim3(Bb, 2, 4), 128, 0, stream>>>(enc, alpha_ptr, c_ptr);
    xc_kernel<<<Bb, 256, 0, stream>>>(dec_input, emb, c_ptr, xc_ptr);

    // gi = xc @ W_ih^T   : N=3072, K=2048, 4-way block k-split (wave slice 128)
    gemm64_kernel<<<dim3(3 * Hh / 64, 4), 256, 65536, stream>>>(
        xc_ptr, W_ih, nullptr, gi_ptr, 3 * Hh, Ee + Hh, 1);
    // gh = h_last @ W_hh^T : N=3072, K=1024, 2-way block k-split (wave slice 128)
    gemm64_kernel<<<dim3(3 * Hh / 64, 2), 256, 65536, stream>>>(
        dec_hidden, W_hh, nullptr, gh_ptr, 3 * Hh, Hh, 1);

    gru_kernel<<<(Bb * Hh) / 256, 256, 0, stream>>>(gi_ptr, gh_ptr, b_ih, b_hh,
                                                    dec_hidden, h_new);

    // logits = h_new @ W_out^T + b_out : N=32000, K=1024, no k-split (wave slice 256)
    gemm64_kernel<<<dim3(Vv / 64, 1), 256, 65536, stream>>>(
        h_new, W_out, b_out, logits, Vv, Hh, 0);
}

// Round 2
// 481.609 us; speedup vs baseline: 1.1856x; 1.1856x over previous
//
#include <hip/hip_runtime.h>
#include <math.h>

// Problem constants
#define Vv 32000
#define Ee 1024
#define Hh 1024
#define Aa 10
#define Ss 512
#define Bb 64

typedef __attribute__((ext_vector_type(8))) short bf16x8;   // 8 bf16 = 4 VGPRs
typedef __attribute__((ext_vector_type(4))) short s16x4;
typedef __attribute__((ext_vector_type(4))) float f32x4;

// fp32 -> bf16 (round-to-nearest-even), bit trick
__device__ inline short f2bf(float f) {
    union { float f; unsigned int u; } v;
    v.f = f;
    unsigned int r = (v.u + 0x7FFFu + ((v.u >> 16) & 1u)) >> 16;
    return (short)r;
}

__device__ inline bf16x8 cvt8(float4 lo, float4 hi) {
    bf16x8 r;
    r[0] = f2bf(lo.x); r[1] = f2bf(lo.y); r[2] = f2bf(lo.z); r[3] = f2bf(lo.w);
    r[4] = f2bf(hi.x); r[5] = f2bf(hi.y); r[6] = f2bf(hi.z); r[7] = f2bf(hi.w);
    return r;
}

// ---------------------------------------------------------------------------
// hpart[b][a] = sum_k Wa1[a][k] * h_last[b][k]  (k in [0,1024): "hh" half)
// grid(64), block(256)
__global__ __launch_bounds__(256) void hpart_kernel(const float* __restrict__ Wa1,
                                                    const float* __restrict__ h,
                                                    float* __restrict__ hpart) {
    __shared__ float red[256];
    const int b = blockIdx.x, t = threadIdx.x;
    float p[Aa];
#pragma unroll
    for (int a = 0; a < Aa; a++) p[a] = 0.f;
    for (int k = t; k < Hh; k += 256) {
        float hv = h[b * Hh + k];
#pragma unroll
        for (int a = 0; a < Aa; a++) p[a] += Wa1[a * (2 * Hh) + k] * hv;
    }
    for (int a = 0; a < Aa; a++) {
        red[t] = p[a];
        __syncthreads();
        for (int o = 128; o > 0; o >>= 1) {
            if (t < o) red[t] += red[t + o];
            __syncthreads();
        }
        if (t == 0) hpart[b * 16 + a] = red[0];
        __syncthreads();
    }
}

// ---------------------------------------------------------------------------
// scores: e[s*64+b] = sum_a Wa2[a]*tanh(hpart[b][a] + dot(Wa1_enc[a], enc[s,b,:]))
// grid(512), block(256)
__global__ __launch_bounds__(256) void scores_kernel(const float* __restrict__ enc,
                                                     const float* __restrict__ Wa1,
                                                     const float* __restrict__ Wa2,
                                                     const float* __restrict__ hpart,
                                                     float* __restrict__ e_out) {
    __shared__ float es[64][65];
    __shared__ float red[4][64][11];
    const int t = threadIdx.x;
    const int m0 = blockIdx.x * 64;
    const int q = __builtin_amdgcn_readfirstlane((int)(t >> 6));
    const int lane = t & 63;
    const float4* enc4 = (const float4*)enc;

    float acc[Aa];
#pragma unroll
    for (int a = 0; a < Aa; a++) acc[a] = 0.f;

    for (int c = 0; c < 16; c++) {
#pragma unroll
        for (int p = 0; p < 4; p++) {
            int idx = t + p * 256;
            int r = idx >> 4, kq = idx & 15;
            float4 v = enc4[(size_t)(m0 + r) * 256 + c * 16 + kq];
            es[r][kq * 4 + 0] = v.x;
            es[r][kq * 4 + 1] = v.y;
            es[r][kq * 4 + 2] = v.z;
            es[r][kq * 4 + 3] = v.w;
        }
        __syncthreads();
        const int kbase = Hh + c * 64 + q * 16;
#pragma unroll
        for (int j = 0; j < 16; j++) {
            float ev = es[lane][q * 16 + j];
#pragma unroll
            for (int a = 0; a < Aa; a++)
                acc[a] += Wa1[a * (2 * Hh) + kbase + j] * ev;
        }
        __syncthreads();
    }
#pragma unroll
    for (int a = 0; a < Aa; a++) red[q][lane][a] = acc[a];
    __syncthreads();
    if (t < 64) {
        float ev = 0.f;
#pragma unroll
        for (int a = 0; a < Aa; a++) {
            float tot = red[0][t][a] + red[1][t][a] + red[2][t][a] + red[3][t][a]
                        + hpart[t * 16 + a];
            ev += Wa2[a] * tanhf(tot);
        }
        e_out[m0 + t] = ev;
    }
}

// ---------------------------------------------------------------------------
// softmax over S per column b. grid(64), block(512)
__global__ __launch_bounds__(512) void softmax_kernel(const float* __restrict__ e,
                                                      float* __restrict__ alpha) {
    __shared__ float red[512];
    const int b = blockIdx.x, s = threadIdx.x;
    float v = e[s * Bb + b];
    red[s] = v;
    __syncthreads();
    for (int o = 256; o > 0; o >>= 1) {
        if (s < o) red[s] = fmaxf(red[s], red[s + o]);
        __syncthreads();
    }
    float m = red[0];
    __syncthreads();
    float ex = expf(v - m);
    red[s] = ex;
    __syncthreads();
    for (int o = 256; o > 0; o >>= 1) {
        if (s < o) red[s] += red[s + o];
        __syncthreads();
    }
    float inv = 1.f / red[0];
    alpha[s * Bb + b] = ex * inv;
}

// ---------------------------------------------------------------------------
// context: c[b][h] = sum_s alpha[s,b]*enc[s,b,h]
// grid(64,2,4), block(128); s-split partials via global f32 atomics (c zeroed)
__global__ __launch_bounds__(128) void context_kernel(const float* __restrict__ enc,
                                                      const float* __restrict__ alpha,
                                                      float* __restrict__ c) {
    const int b = blockIdx.x, hc = blockIdx.y, sc = blockIdx.z;
    const int h4 = hc * 128 + threadIdx.x;
    const float4* enc4 = (const float4*)enc;
    float4 acc = {0.f, 0.f, 0.f, 0.f};
    const int s0 = sc * 128;
    for (int s = s0; s < s0 + 128; ++s) {
        float a = alpha[s * Bb + b];
        float4 ev = enc4[(size_t)(s * Bb + b) * 256 + h4];
        acc.x += a * ev.x;
        acc.y += a * ev.y;
        acc.z += a * ev.z;
        acc.w += a * ev.w;
    }
    float* cp = c + b * Hh + h4 * 4;
    atomicAdd(cp + 0, acc.x);
    atomicAdd(cp + 1, acc.y);
    atomicAdd(cp + 2, acc.z);
    atomicAdd(cp + 3, acc.w);
}

// ---------------------------------------------------------------------------
// Build bf16 A-operands: xcb[b] = bf16([emb[tok_b] | c[b]]), hb[b] = bf16(h[b])
// grid(64), block(256)
__global__ __launch_bounds__(256) void xc_kernel(const int* __restrict__ dec_input,
                                                 const float* __restrict__ emb,
                                                 const float* __restrict__ c,
                                                 const float* __restrict__ h,
                                                 short* __restrict__ xcb,
                                                 short* __restrict__ hb) {
    const int b = blockIdx.x, t = threadIdx.x;
    const int tok = dec_input[b];
    float4 ev = ((const float4*)(emb + (size_t)tok * Ee))[t];
    float4 cv = ((const float4*)(c + (size_t)b * Hh))[t];
    float4 hv = ((const float4*)(h + (size_t)b * Hh))[t];
    s16x4 e4 = {f2bf(ev.x), f2bf(ev.y), f2bf(ev.z), f2bf(ev.w)};
    s16x4 c4 = {f2bf(cv.x), f2bf(cv.y), f2bf(cv.z), f2bf(cv.w)};
    s16x4 h4 = {f2bf(hv.x), f2bf(hv.y), f2bf(hv.z), f2bf(hv.w)};
    ((s16x4*)(xcb + (size_t)b * 2048))[t] = e4;
    ((s16x4*)(xcb + (size_t)b * 2048 + 1024))[t] = c4;
    ((s16x4*)(hb + (size_t)b * 1024))[t] = h4;
}

// ---------------------------------------------------------------------------
// Streaming MFMA GEMM: C[64][N] (+)= bf16(A)[64][K] @ bf16(W[N][K])^T (+bias)
// No LDS. Block=256 (4 waves); wave w owns 16 cols (n0 = blk*64 + w*16) and
// all 64 rows as 4 16x16 MFMA tiles. W fp32 is loaded straight to registers
// (two float4 per lane per 32-k = the exact B-fragment: row n0+(lane&15),
// k = kb+(lane>>4)*8..+7 -> per-row 128B contiguous across the wave),
// converted to bf16 in-register, and fed to mfma_f32_16x16x32_bf16.
// A (bf16, 64 rows) is L2-resident; loaded per tile as one 16B frag.
// Optional k-split across blockIdx.y (atomic accumulate; C pre-zeroed).
__global__ __launch_bounds__(256) void gemm_mfma_kernel(
    const short* __restrict__ Abf,  // [64][K] bf16
    const float* __restrict__ W,    // [N][K] fp32
    const float* __restrict__ bias, // or nullptr
    float* __restrict__ C,          // [64][N]
    int N, int K, int Klen, int doAtomic) {
    const int t = threadIdx.x;
    const int w = t >> 6, lane = t & 63;
    const int col = lane & 15, quad = lane >> 4;
    const int n0 = blockIdx.x * 64 + w * 16;
    const int kb0 = blockIdx.y * Klen;

    f32x4 acc[4];
#pragma unroll
    for (int mt = 0; mt < 4; mt++) acc[mt] = (f32x4){0.f, 0.f, 0.f, 0.f};

    const float* wrow = W + (size_t)(n0 + col) * K + kb0 + quad * 8;
    const short* arow = Abf + (size_t)col * K + kb0 + quad * 8;

    for (int kb = 0; kb < Klen; kb += 64) {
        float4 w0 = *(const float4*)(wrow + kb);
        float4 w1 = *(const float4*)(wrow + kb + 4);
        float4 w2 = *(const float4*)(wrow + kb + 32);
        float4 w3 = *(const float4*)(wrow + kb + 36);
        bf16x8 bf0 = cvt8(w0, w1);
        bf16x8 bf1 = cvt8(w2, w3);
        bf16x8 a0[4], a1[4];
#pragma unroll
        for (int mt = 0; mt < 4; mt++) {
            a0[mt] = *(const bf16x8*)(arow + (size_t)mt * 16 * K + kb);
            a1[mt] = *(const bf16x8*)(arow + (size_t)mt * 16 * K + kb + 32);
        }
#pragma unroll
        for (int mt = 0; mt < 4; mt++)
            acc[mt] = __builtin_amdgcn_mfma_f32_16x16x32_bf16(a0[mt], bf0, acc[mt], 0, 0, 0);
#pragma unroll
        for (int mt = 0; mt < 4; mt++)
            acc[mt] = __builtin_amdgcn_mfma_f32_16x16x32_bf16(a1[mt], bf1, acc[mt], 0, 0, 0);
    }

    // C/D layout: reg r, lane -> row = quad*4 + r (within tile), col = lane&15
    const float bv = (bias != nullptr) ? bias[n0 + col] : 0.f;
#pragma unroll
    for (int mt = 0; mt < 4; mt++) {
#pragma unroll
        for (int r = 0; r < 4; r++) {
            int m = mt * 16 + quad * 4 + r;
            size_t off = (size_t)m * N + n0 + col;
            if (doAtomic) atomicAdd(&C[off], acc[mt][r]);
            else C[off] = acc[mt][r] + bv;
        }
    }
}

// ---------------------------------------------------------------------------
// GRU cell elementwise; gi/gh lack biases (added here). Also emits bf16 h_new.
// grid(256), block(256)
__global__ __launch_bounds__(256) void gru_kernel(const float* __restrict__ gi,
                                                  const float* __restrict__ gh,
                                                  const float* __restrict__ b_ih,
                                                  const float* __restrict__ b_hh,
                                                  const float* __restrict__ h,
                                                  float* __restrict__ h_new,
                                                  short* __restrict__ hnb) {
    const int idx = blockIdx.x * 256 + threadIdx.x;
    const int b = idx >> 10, j = idx & 1023;
    const size_t base = (size_t)b * (3 * Hh);
    float ir = gi[base + j] + b_ih[j];
    float iz = gi[base + Hh + j] + b_ih[Hh + j];
    float in_ = gi[base + 2 * Hh + j] + b_ih[2 * Hh + j];
    float hr = gh[base + j] + b_hh[j];
    float hz = gh[base + Hh + j] + b_hh[Hh + j];
    float hn = gh[base + 2 * Hh + j] + b_hh[2 * Hh + j];
    float r = 1.f / (1.f + expf(-(ir + hr)));
    float z = 1.f / (1.f + expf(-(iz + hz)));
    float n = tanhf(in_ + r * hn);
    float val = (1.f - z) * n + z * h[idx];
    h_new[idx] = val;
    hnb[idx] = f2bf(val);
}

// ---------------------------------------------------------------------------
extern "C" void kernel_launch(void* const* d_in, const int* in_sizes, int n_in,
                              void* d_out, int out_size, void* d_ws, size_t ws_size,
                              hipStream_t stream) {
    const int* dec_input = (const int*)d_in[0];
    const float* dec_hidden = (const float*)d_in[1];
    const float* enc = (const float*)d_in[2];
    const float* emb = (const float*)d_in[3];
    const float* Wa1 = (const float*)d_in[4];
    const float* Wa2 = (const float*)d_in[5];
    const float* W_ih = (const float*)d_in[6];
    const float* W_hh = (const float*)d_in[7];
    const float* b_ih = (const float*)d_in[8];
    const float* b_hh = (const float*)d_in[9];
    const float* W_out = (const float*)d_in[10];
    const float* b_out = (const float*)d_in[11];

    float* out = (float*)d_out;
    float* logits = out;                  // (B,V)
    float* h_new = out + (size_t)Bb * Vv; // (1,B,H)

    float* ws = (float*)d_ws;
    float* e_ptr = ws;                    // 32768
    float* alpha_ptr = ws + 32768;        // 32768
    float* hpart_ptr = ws + 65536;        // 1024
    float* c_ptr = ws + 66560;            // 65536
    float* gi_ptr = ws + 132096;          // 196608
    float* gh_ptr = ws + 328704;          // 196608
    short* xcb_ptr = (short*)(ws + 525312);   // 131072 shorts (65536 f)
    short* hb_ptr = (short*)(ws + 590848);    // 65536 shorts  (32768 f)
    short* hnb_ptr = (short*)(ws + 623616);   // 65536 shorts  (32768 f)
    // total: 656384 floats = 2.63 MB

    // zero atomic-accumulated buffers (c, gi, gh are contiguous ws ranges)
    hipMemsetAsync(c_ptr, 0, (size_t)Bb * Hh * sizeof(float), stream);
    hipMemsetAsync(gi_ptr, 0, (size_t)2 * Bb * 3 * Hh * sizeof(float), stream);

    hpart_kernel<<<Bb, 256, 0, stream>>>(Wa1, dec_hidden, hpart_ptr);
    scores_kernel<<<(Ss * Bb) / 64, 256, 0, stream>>>(enc, Wa1, Wa2, hpart_ptr, e_ptr);
    softmax_kernel<<<Bb, 512, 0, stream>>>(e_ptr, alpha_ptr);
    context_kernel<<<dim3(Bb, 2, 4), 128, 0, stream>>>(enc, alpha_ptr, c_ptr);
    xc_kernel<<<Bb, 256, 0, stream>>>(dec_input, emb, c_ptr, dec_hidden, xcb_ptr, hb_ptr);

    // gi = xc @ W_ih^T : N=3072, K=2048, k-split 8 (Klen=256), atomic
    gemm_mfma_kernel<<<dim3(3 * Hh / 64, 8), 256, 0, stream>>>(
        xcb_ptr, W_ih, nullptr, gi_ptr, 3 * Hh, Ee + Hh, 256, 1);
    // gh = h @ W_hh^T : N=3072, K=1024, k-split 4 (Klen=256), atomic
    gemm_mfma_kernel<<<dim3(3 * Hh / 64, 4), 256, 0, stream>>>(
        hb_ptr, W_hh, nullptr, gh_ptr, 3 * Hh, Hh, 256, 1);

    gru_kernel<<<(Bb * Hh) / 256, 256, 0, stream>>>(gi_ptr, gh_ptr, b_ih, b_hh,
                                                    dec_hidden, h_new, hnb_ptr);

    // logits = h_new @ W_out^T + b_out : N=32000, K=1024, no split
    gemm_mfma_kernel<<<dim3(Vv / 64, 1), 256, 0, stream>>>(
        hnb_ptr, W_out, b_out, logits, Vv, Hh, 1024, 0);
}

// Round 3
// 448.048 us; speedup vs baseline: 1.2744x; 1.0749x over previous
//
#include <hip/hip_runtime.h>
#include <math.h>

// Problem constants
#define Vv 32000
#define Ee 1024
#define Hh 1024
#define Aa 10
#define Ss 512
#define Bb 64
#define Mm (Ss * Bb)   // 32768 rows of enc viewed as (s*64+b)

typedef __attribute__((ext_vector_type(8))) short bf16x8;   // 8 bf16 = 4 VGPRs
typedef __attribute__((ext_vector_type(4))) short s16x4;
typedef __attribute__((ext_vector_type(4))) float f32x4;

// fp32 -> bf16 (round-to-nearest-even), bit trick
__device__ inline short f2bf(float f) {
    union { float f; unsigned int u; } v;
    v.f = f;
    unsigned int r = (v.u + 0x7FFFu + ((v.u >> 16) & 1u)) >> 16;
    return (short)r;
}

__device__ inline bf16x8 cvt8(float4 lo, float4 hi) {
    bf16x8 r;
    r[0] = f2bf(lo.x); r[1] = f2bf(lo.y); r[2] = f2bf(lo.z); r[3] = f2bf(lo.w);
    r[4] = f2bf(hi.x); r[5] = f2bf(hi.y); r[6] = f2bf(hi.z); r[7] = f2bf(hi.w);
    return r;
}

// ---------------------------------------------------------------------------
// hpart[b][a] = sum_k Wa1[a][k] * h_last[b][k]  (k in [0,1024): "hh" half)
// grid(64), block(256)
__global__ __launch_bounds__(256) void hpart_kernel(const float* __restrict__ Wa1,
                                                    const float* __restrict__ h,
                                                    float* __restrict__ hpart) {
    __shared__ float red[256];
    const int b = blockIdx.x, t = threadIdx.x;
    float p[Aa];
#pragma unroll
    for (int a = 0; a < Aa; a++) p[a] = 0.f;
    for (int k = t; k < Hh; k += 256) {
        float hv = h[b * Hh + k];
#pragma unroll
        for (int a = 0; a < Aa; a++) p[a] += Wa1[a * (2 * Hh) + k] * hv;
    }
    for (int a = 0; a < Aa; a++) {
        red[t] = p[a];
        __syncthreads();
        for (int o = 128; o > 0; o >>= 1) {
            if (t < o) red[t] += red[t + o];
            __syncthreads();
        }
        if (t == 0) hpart[b * 16 + a] = red[0];
        __syncthreads();
    }
}

// ---------------------------------------------------------------------------
// scores GEMM: epre[p][m][16] = enc[m][kp] @ Wa1_enc[kp]^T  (partial over k-split)
// No LDS. Wave w of 4 owns m-tile (blockIdx.x*4+w)*16; blockIdx.y = k-split p
// (Klen = 512). A (enc fp32) and B (Wa1 enc-half fp32) converted to bf16 in
// registers, fed to mfma_f32_16x16x32_bf16. B cols >= 10 are zero padding.
// grid(512, 2), block(256)
__global__ __launch_bounds__(256) void scores_mfma_kernel(
    const float* __restrict__ enc,
    const float* __restrict__ Wa1,
    float* __restrict__ epre) {   // [2][Mm][16]
    const int t = threadIdx.x;
    const int w = t >> 6, lane = t & 63;
    const int col = lane & 15, quad = lane >> 4;
    const int m0 = (blockIdx.x * 4 + w) * 16;
    const int p = blockIdx.y;
    const int kb0 = p * 512;

    f32x4 acc = {0.f, 0.f, 0.f, 0.f};
    const int wa_row = (col < Aa) ? col : 0;
    const float* wrow = Wa1 + (size_t)wa_row * (2 * Hh) + Hh + kb0 + quad * 8;
    const float* arow = enc + (size_t)(m0 + col) * Hh + kb0 + quad * 8;
    const bool valid = (col < Aa);

#pragma unroll
    for (int c = 0; c < 16; c++) {  // 16 chunks of 32 k
        float4 a0 = *(const float4*)(arow + c * 32);
        float4 a1 = *(const float4*)(arow + c * 32 + 4);
        bf16x8 af = cvt8(a0, a1);
        bf16x8 bf;
        if (valid) {
            float4 b0 = *(const float4*)(wrow + c * 32);
            float4 b1 = *(const float4*)(wrow + c * 32 + 4);
            bf = cvt8(b0, b1);
        } else {
            bf = (bf16x8){0, 0, 0, 0, 0, 0, 0, 0};
        }
        acc = __builtin_amdgcn_mfma_f32_16x16x32_bf16(af, bf, acc, 0, 0, 0);
    }
    // C/D layout: col = lane&15, row = quad*4 + r
    float* out = epre + ((size_t)p * Mm + m0) * 16;
#pragma unroll
    for (int r = 0; r < 4; r++)
        out[(quad * 4 + r) * 16 + col] = acc[r];
}

// ---------------------------------------------------------------------------
// fused e-compute + softmax over S per column b.
// e[s,b] = sum_a Wa2[a]*tanh(epre0+epre1 + hpart[b][a]); alpha = softmax_s(e)
// grid(64), block(512)
__global__ __launch_bounds__(512) void softmax_kernel(const float* __restrict__ epre,
                                                      const float* __restrict__ hpart,
                                                      const float* __restrict__ Wa2,
                                                      float* __restrict__ alpha) {
    __shared__ float red[512];
    const int b = blockIdx.x, s = threadIdx.x;
    const int m = s * Bb + b;
    float v = 0.f;
#pragma unroll
    for (int a = 0; a < Aa; a++) {
        float tot = hpart[b * 16 + a] + epre[(size_t)m * 16 + a]
                    + epre[((size_t)Mm + m) * 16 + a];
        v += Wa2[a] * tanhf(tot);
    }
    red[s] = v;
    __syncthreads();
    for (int o = 256; o > 0; o >>= 1) {
        if (s < o) red[s] = fmaxf(red[s], red[s + o]);
        __syncthreads();
    }
    float mx = red[0];
    __syncthreads();
    float ex = expf(v - mx);
    red[s] = ex;
    __syncthreads();
    for (int o = 256; o > 0; o >>= 1) {
        if (s < o) red[s] += red[s + o];
        __syncthreads();
    }
    float inv = 1.f / red[0];
    alpha[s * Bb + b] = ex * inv;
}

// ---------------------------------------------------------------------------
// context partials: cpart[sc][b][h] = sum_{s in chunk sc} alpha[s,b]*enc[s,b,h]
// grid(64,16), block(256): thread = float4 index h4 in [0,256)
__global__ __launch_bounds__(256) void context_kernel(const float* __restrict__ enc,
                                                      const float* __restrict__ alpha,
                                                      float* __restrict__ cpart) {
    const int b = blockIdx.x, sc = blockIdx.y;
    const int h4 = threadIdx.x;
    const float4* enc4 = (const float4*)enc;
    float4 acc = {0.f, 0.f, 0.f, 0.f};
    const int s0 = sc * 32;
    for (int s = s0; s < s0 + 32; ++s) {
        float a = alpha[s * Bb + b];
        float4 ev = enc4[(size_t)(s * Bb + b) * 256 + h4];
        acc.x += a * ev.x;
        acc.y += a * ev.y;
        acc.z += a * ev.z;
        acc.w += a * ev.w;
    }
    ((float4*)cpart)[((size_t)sc * Bb + b) * 256 + h4] = acc;
}

// ---------------------------------------------------------------------------
// xc: reduce 16 context partials, build bf16 A-operands:
// xcb[b] = bf16([emb[tok_b] | c[b]]), hb[b] = bf16(h[b])
// grid(64), block(256)
__global__ __launch_bounds__(256) void xc_kernel(const int* __restrict__ dec_input,
                                                 const float* __restrict__ emb,
                                                 const float* __restrict__ cpart,
                                                 const float* __restrict__ h,
                                                 short* __restrict__ xcb,
                                                 short* __restrict__ hb) {
    const int b = blockIdx.x, t = threadIdx.x;
    const int tok = dec_input[b];
    float4 cv = {0.f, 0.f, 0.f, 0.f};
#pragma unroll
    for (int p = 0; p < 16; p++) {
        float4 v = ((const float4*)cpart)[((size_t)p * Bb + b) * 256 + t];
        cv.x += v.x; cv.y += v.y; cv.z += v.z; cv.w += v.w;
    }
    float4 ev = ((const float4*)(emb + (size_t)tok * Ee))[t];
    float4 hv = ((const float4*)(h + (size_t)b * Hh))[t];
    s16x4 e4 = {f2bf(ev.x), f2bf(ev.y), f2bf(ev.z), f2bf(ev.w)};
    s16x4 c4 = {f2bf(cv.x), f2bf(cv.y), f2bf(cv.z), f2bf(cv.w)};
    s16x4 h4v = {f2bf(hv.x), f2bf(hv.y), f2bf(hv.z), f2bf(hv.w)};
    ((s16x4*)(xcb + (size_t)b * 2048))[t] = e4;
    ((s16x4*)(xcb + (size_t)b * 2048 + 1024))[t] = c4;
    ((s16x4*)(hb + (size_t)b * 1024))[t] = h4v;
}

// ---------------------------------------------------------------------------
// Streaming MFMA GEMM: C[p][64][N] = bf16(A)[64][Kp] @ bf16(W[N][Kp])^T (+bias)
// No LDS. Wave w owns 16 cols (n0=blk*64+w*16), 64 rows as 4 16x16 tiles.
// blockIdx.y = k-split p (Klen each); partials written to C + p*64*N.
__global__ __launch_bounds__(256) void gemm_mfma_kernel(
    const short* __restrict__ Abf,  // [64][K] bf16
    const float* __restrict__ W,    // [N][K] fp32
    const float* __restrict__ bias, // or nullptr (only valid when ksplit==1)
    float* __restrict__ C,
    int N, int K, int Klen) {
    const int t = threadIdx.x;
    const int w = t >> 6, lane = t & 63;
    const int col = lane & 15, quad = lane >> 4;
    const int n0 = blockIdx.x * 64 + w * 16;
    const int kb0 = blockIdx.y * Klen;

    f32x4 acc[4];
#pragma unroll
    for (int mt = 0; mt < 4; mt++) acc[mt] = (f32x4){0.f, 0.f, 0.f, 0.f};

    const float* wrow = W + (size_t)(n0 + col) * K + kb0 + quad * 8;
    const short* arow = Abf + (size_t)col * K + kb0 + quad * 8;

    for (int kb = 0; kb < Klen; kb += 64) {
        float4 w0 = *(const float4*)(wrow + kb);
        float4 w1 = *(const float4*)(wrow + kb + 4);
        float4 w2 = *(const float4*)(wrow + kb + 32);
        float4 w3 = *(const float4*)(wrow + kb + 36);
        bf16x8 bf0 = cvt8(w0, w1);
        bf16x8 bf1 = cvt8(w2, w3);
        bf16x8 a0[4], a1[4];
#pragma unroll
        for (int mt = 0; mt < 4; mt++) {
            a0[mt] = *(const bf16x8*)(arow + (size_t)mt * 16 * K + kb);
            a1[mt] = *(const bf16x8*)(arow + (size_t)mt * 16 * K + kb + 32);
        }
#pragma unroll
        for (int mt = 0; mt < 4; mt++)
            acc[mt] = __builtin_amdgcn_mfma_f32_16x16x32_bf16(a0[mt], bf0, acc[mt], 0, 0, 0);
#pragma unroll
        for (int mt = 0; mt < 4; mt++)
            acc[mt] = __builtin_amdgcn_mfma_f32_16x16x32_bf16(a1[mt], bf1, acc[mt], 0, 0, 0);
    }

    const float bv = (bias != nullptr) ? bias[n0 + col] : 0.f;
    float* Cp = C + (size_t)blockIdx.y * 64 * N;
#pragma unroll
    for (int mt = 0; mt < 4; mt++) {
#pragma unroll
        for (int r = 0; r < 4; r++) {
            int m = mt * 16 + quad * 4 + r;
            Cp[(size_t)m * N + n0 + col] = acc[mt][r] + bv;
        }
    }
}

// ---------------------------------------------------------------------------
// GRU cell elementwise; sums gi (8) / gh (8) k-split partials, adds biases,
// emits fp32 h_new and bf16 h_new.
// grid(256), block(256)
__global__ __launch_bounds__(256) void gru_kernel(const float* __restrict__ gip,
                                                  const float* __restrict__ ghp,
                                                  const float* __restrict__ b_ih,
                                                  const float* __restrict__ b_hh,
                                                  const float* __restrict__ h,
                                                  float* __restrict__ h_new,
                                                  short* __restrict__ hnb) {
    const int idx = blockIdx.x * 256 + threadIdx.x;
    const int b = idx >> 10, j = idx & 1023;
    const size_t base = (size_t)b * (3 * Hh);
    float ir = b_ih[j], iz = b_ih[Hh + j], in_ = b_ih[2 * Hh + j];
    float hr = b_hh[j], hz = b_hh[Hh + j], hn = b_hh[2 * Hh + j];
#pragma unroll
    for (int p = 0; p < 8; p++) {
        const float* g = gip + (size_t)p * Bb * 3 * Hh + base;
        ir += g[j]; iz += g[Hh + j]; in_ += g[2 * Hh + j];
    }
#pragma unroll
    for (int p = 0; p < 8; p++) {
        const float* g = ghp + (size_t)p * Bb * 3 * Hh + base;
        hr += g[j]; hz += g[Hh + j]; hn += g[2 * Hh + j];
    }
    float r = 1.f / (1.f + expf(-(ir + hr)));
    float z = 1.f / (1.f + expf(-(iz + hz)));
    float n = tanhf(in_ + r * hn);
    float val = (1.f - z) * n + z * h[idx];
    h_new[idx] = val;
    hnb[idx] = f2bf(val);
}

// ---------------------------------------------------------------------------
extern "C" void kernel_launch(void* const* d_in, const int* in_sizes, int n_in,
                              void* d_out, int out_size, void* d_ws, size_t ws_size,
                              hipStream_t stream) {
    const int* dec_input = (const int*)d_in[0];
    const float* dec_hidden = (const float*)d_in[1];
    const float* enc = (const float*)d_in[2];
    const float* emb = (const float*)d_in[3];
    const float* Wa1 = (const float*)d_in[4];
    const float* Wa2 = (const float*)d_in[5];
    const float* W_ih = (const float*)d_in[6];
    const float* W_hh = (const float*)d_in[7];
    const float* b_ih = (const float*)d_in[8];
    const float* b_hh = (const float*)d_in[9];
    const float* W_out = (const float*)d_in[10];
    const float* b_out = (const float*)d_in[11];

    float* out = (float*)d_out;
    float* logits = out;                  // (B,V)
    float* h_new = out + (size_t)Bb * Vv; // (1,B,H)

    // Workspace layout (floats), lifetime-aliased:
    //   alpha     [0, 32768)
    //   hpart     [32768, 33792)
    //   xcb(bf16) [33792, 99328)   = 131072 shorts
    //   hb (bf16) [99328, 132096)  = 65536 shorts
    //   hnb(bf16) [132096, 164864) = 65536 shorts
    //   region1   [164864, +1572864): epre (2*32768*16=1048576) then gip (8*196608)
    //   region2   [1737728, +1572864): cpart (16*65536=1048576) then ghp (8*196608)
    float* ws = (float*)d_ws;
    float* alpha_ptr = ws;
    float* hpart_ptr = ws + 32768;
    short* xcb_ptr = (short*)(ws + 33792);
    short* hb_ptr = (short*)(ws + 99328);
    short* hnb_ptr = (short*)(ws + 132096);
    float* region1 = ws + 164864;
    float* region2 = ws + 1737728;
    float* epre_ptr = region1;   // dead after softmax
    float* gip_ptr = region1;    // written after xc
    float* cpart_ptr = region2;  // dead after xc
    float* ghp_ptr = region2;    // written after xc

    hpart_kernel<<<Bb, 256, 0, stream>>>(Wa1, dec_hidden, hpart_ptr);
    scores_mfma_kernel<<<dim3(Mm / 64, 2), 256, 0, stream>>>(enc, Wa1, epre_ptr);
    softmax_kernel<<<Bb, 512, 0, stream>>>(epre_ptr, hpart_ptr, Wa2, alpha_ptr);
    context_kernel<<<dim3(Bb, 16), 256, 0, stream>>>(enc, alpha_ptr, cpart_ptr);
    xc_kernel<<<Bb, 256, 0, stream>>>(dec_input, emb, cpart_ptr, dec_hidden,
                                      xcb_ptr, hb_ptr);

    // gi = xc @ W_ih^T : N=3072, K=2048, k-split 8 (Klen=256)
    gemm_mfma_kernel<<<dim3(3 * Hh / 64, 8), 256, 0, stream>>>(
        xcb_ptr, W_ih, nullptr, gip_ptr, 3 * Hh, Ee + Hh, 256);
    // gh = h @ W_hh^T : N=3072, K=1024, k-split 8 (Klen=128)
    gemm_mfma_kernel<<<dim3(3 * Hh / 64, 8), 256, 0, stream>>>(
        hb_ptr, W_hh, nullptr, ghp_ptr, 3 * Hh, Hh, 128);

    gru_kernel<<<(Bb * Hh) / 256, 256, 0, stream>>>(gip_ptr, ghp_ptr, b_ih, b_hh,
                                                    dec_hidden, h_new, hnb_ptr);

    // logits = h_new @ W_out^T + b_out : N=32000, K=1024, no split
    gemm_mfma_kernel<<<dim3(Vv / 64, 1), 256, 0, stream>>>(
        hnb_ptr, W_out, b_out, logits, Vv, Hh, 1024);
}